// Round 1
// baseline (486.401 us; speedup 1.0000x reference)
//
#include <hip/hip_runtime.h>
#include <hip/hip_bf16.h>

#define DEV_INLINE __device__ __forceinline__

static DEV_INLINE float4 ld4(const float* p){ return *reinterpret_cast<const float4*>(p); }
static DEV_INLINE void st4(float* p, float4 v){ *reinterpret_cast<float4*>(p) = v; }

#define GNUM 64

// ---------------- degree / dinv ----------------
__global__ void k_degree(const int* __restrict__ dst, int E, int* __restrict__ deg){
    int i = blockIdx.x*256 + threadIdx.x;
    if (i < E) atomicAdd(&deg[dst[i]], 1);
}

__global__ void k_dinv(const int* __restrict__ deg, float* __restrict__ dinv, int N){
    int i = blockIdx.x*256 + threadIdx.x;
    if (i < N) dinv[i] = rsqrtf((float)(deg[i] + 1));   // +1 = self loop, always >=1
}

// ---------------- exclusive scan of deg -> row_start (3 kernels) ----------------
__global__ void k_scan_blocks(const int* __restrict__ deg, int* __restrict__ rs,
                              int* __restrict__ bsum, int N){
    __shared__ int ws[4];
    int t = threadIdx.x;
    int base = blockIdx.x*1024 + t*4;
    int v0 = (base+0<N)? deg[base+0]:0;
    int v1 = (base+1<N)? deg[base+1]:0;
    int v2 = (base+2<N)? deg[base+2]:0;
    int v3 = (base+3<N)? deg[base+3]:0;
    int tsum = v0+v1+v2+v3;
    int lane = t & 63, w = t >> 6;
    int x = tsum;
    for (int off=1; off<64; off<<=1){
        int yv = __shfl_up(x, off);
        if (lane >= off) x += yv;
    }
    if (lane == 63) ws[w] = x;
    __syncthreads();
    if (t == 0){
        int a = 0;
        for (int i=0;i<4;i++){ int tmp=ws[i]; ws[i]=a; a+=tmp; }
    }
    __syncthreads();
    int ex = x - tsum + ws[w];     // exclusive prefix for this thread within block
    if (base+0<N) rs[base+0] = ex; ex += v0;
    if (base+1<N) rs[base+1] = ex; ex += v1;
    if (base+2<N) rs[base+2] = ex; ex += v2;
    if (base+3<N) rs[base+3] = ex;
    if (t == 255) bsum[blockIdx.x] = ws[3] + x;
}

__global__ void k_scan_mid(int* __restrict__ bsum, int B){  // B <= 64
    int lane = threadIdx.x;
    int v = (lane < B)? bsum[lane] : 0;
    int x = v;
    for (int off=1; off<64; off<<=1){
        int yv = __shfl_up(x, off);
        if (lane >= off) x += yv;
    }
    if (lane < B) bsum[lane] = x - v;  // exclusive
}

__global__ void k_scan_add(int* __restrict__ rs, const int* __restrict__ bsum, int N, int E){
    int base = blockIdx.x*1024 + threadIdx.x*4;
    int off = bsum[blockIdx.x];
    #pragma unroll
    for (int j=0;j<4;j++) if (base+j < N) rs[base+j] += off;
    if (blockIdx.x==0 && threadIdx.x==0) rs[N] = E;
}

__global__ void k_fill(const int* __restrict__ src, const int* __restrict__ dst, int E,
                       const int* __restrict__ rs, int* __restrict__ cur, int* __restrict__ csr){
    int e = blockIdx.x*256 + threadIdx.x;
    if (e < E){
        int d = dst[e];
        int p = atomicAdd(&cur[d], 1);
        csr[rs[d] + p] = src[e];
    }
}

// ---------------- GEMM1: y = (X @ W1) * dinv[row]  (fp32, LDS tiled) ----------------
__global__ __launch_bounds__(256) void k_gemm1(const float* __restrict__ X, const float* __restrict__ W1,
                                               const float* __restrict__ dinv, float* __restrict__ y, int N){
    __shared__ float Ws[128*128];   // 64 KB
    __shared__ float Xs[32*128];    // 16 KB
    int t = threadIdx.x;
    int row0 = blockIdx.x * 32;
    {
        const float4* Wg = (const float4*)W1;
        float4* Wl = (float4*)Ws;
        #pragma unroll
        for (int i=0;i<16;i++) Wl[t + i*256] = Wg[t + i*256];
    }
    {
        float4* Xl = (float4*)Xs;
        const float4* Xg = (const float4*)X;
        #pragma unroll
        for (int i=0;i<4;i++){
            int fi = t + i*256;            // float4 index 0..1023
            int r = fi >> 5;
            float4 v = make_float4(0.f,0.f,0.f,0.f);
            if (row0 + r < N) v = Xg[(size_t)(row0+r)*32 + (fi & 31)];
            Xl[fi] = v;
        }
    }
    __syncthreads();
    int tc = t & 31, tr = t >> 5;  // cols 4tc..4tc+3, rows 4tr..4tr+3
    float4 acc0={0,0,0,0}, acc1={0,0,0,0}, acc2={0,0,0,0}, acc3={0,0,0,0};
    for (int k=0;k<128;k+=4){
        float4 w0 = ld4(&Ws[(k+0)*128 + tc*4]);
        float4 w1 = ld4(&Ws[(k+1)*128 + tc*4]);
        float4 w2 = ld4(&Ws[(k+2)*128 + tc*4]);
        float4 w3 = ld4(&Ws[(k+3)*128 + tc*4]);
        #define ROWSTEP(ACC, RR) { float4 xr = ld4(&Xs[(4*tr+(RR))*128 + k]); \
            ACC.x += xr.x*w0.x + xr.y*w1.x + xr.z*w2.x + xr.w*w3.x; \
            ACC.y += xr.x*w0.y + xr.y*w1.y + xr.z*w2.y + xr.w*w3.y; \
            ACC.z += xr.x*w0.z + xr.y*w1.z + xr.z*w2.z + xr.w*w3.z; \
            ACC.w += xr.x*w0.w + xr.y*w1.w + xr.z*w2.w + xr.w*w3.w; }
        ROWSTEP(acc0,0) ROWSTEP(acc1,1) ROWSTEP(acc2,2) ROWSTEP(acc3,3)
        #undef ROWSTEP
    }
    #define STORESTEP(ACC, RR) { int row = row0 + 4*tr + (RR); if (row < N){ \
        float dv = dinv[row]; float4 o; o.x=ACC.x*dv; o.y=ACC.y*dv; o.z=ACC.z*dv; o.w=ACC.w*dv; \
        st4(&y[(size_t)row*128 + tc*4], o); } }
    STORESTEP(acc0,0) STORESTEP(acc1,1) STORESTEP(acc2,2) STORESTEP(acc3,3)
    #undef STORESTEP
}

// ---------------- aggregate layer 1 + bias + ELU -> h ----------------
// one wave per node; lanes 0..31 take first half of edge list, 32..63 second half.
// each lane holds float4 (16B) of the 512B row; combine halves via shfl_xor(32).
__global__ void k_agg1(const float* __restrict__ y, const float* __restrict__ dinv,
                       const float* __restrict__ b1, const int* __restrict__ rs,
                       const int* __restrict__ csr, float* __restrict__ h, int N){
    int wid = (int)((blockIdx.x * blockDim.x + threadIdx.x) >> 6);
    if (wid >= N) return;
    int lane = threadIdx.x & 63;
    int half = lane >> 5, hl = lane & 31;
    int beg = rs[wid], end = rs[wid+1];
    int len = end - beg;
    int len0 = (len + 1) >> 1;
    int hbeg = beg + (half ? len0 : 0);
    int hlen = half ? (len - len0) : len0;
    float4 acc;
    if (half == 0) acc = ld4(&y[(size_t)wid*128 + hl*4]);   // self loop (added once)
    else acc = make_float4(0.f,0.f,0.f,0.f);
    int iters = (len0 + 31) >> 5;
    for (int c=0;c<iters;c++){
        int o = c*32 + hl;
        int idx = (o < hlen) ? csr[hbeg + o] : 0;
        int nb = hlen - c*32;
        int tmax = len0 - c*32; if (tmax > 32) tmax = 32;
        for (int tt=0; tt<tmax; ++tt){
            int s = __shfl(idx, (half<<5) + tt);
            float4 v = ld4(&y[(size_t)s*128 + hl*4]);
            if (tt < nb){ acc.x+=v.x; acc.y+=v.y; acc.z+=v.z; acc.w+=v.w; }
        }
    }
    acc.x += __shfl_xor(acc.x, 32);
    acc.y += __shfl_xor(acc.y, 32);
    acc.z += __shfl_xor(acc.z, 32);
    acc.w += __shfl_xor(acc.w, 32);
    if (half == 0){
        float dv = dinv[wid];
        float4 bb = ld4(&b1[hl*4]);
        float4 o;
        o.x = dv*acc.x + bb.x; o.y = dv*acc.y + bb.y;
        o.z = dv*acc.z + bb.z; o.w = dv*acc.w + bb.w;
        o.x = o.x > 0.f ? o.x : expm1f(o.x);
        o.y = o.y > 0.f ? o.y : expm1f(o.y);
        o.z = o.z > 0.f ? o.z : expm1f(o.z);
        o.w = o.w > 0.f ? o.w : expm1f(o.w);
        st4(&h[(size_t)wid*128 + hl*4], o);
    }
}

// ---------------- graph boundaries (batch is sorted) ----------------
__global__ void k_bounds(const int* __restrict__ batch, int N, int* __restrict__ gstart){
    int g = threadIdx.x;
    if (g > GNUM) return;
    int lo = 0, hi = N;
    while (lo < hi){ int mid = (lo+hi)>>1; if (batch[mid] < g) lo = mid+1; else hi = mid; }
    gstart[g] = lo;
}

// ---------------- mean-pool partial sums (C = 128 or 32) ----------------
__global__ void k_mpool(const float* __restrict__ srcm, const int* __restrict__ gstart,
                        float* __restrict__ msum, int C){
    int g = blockIdx.x, part = blockIdx.y, P = gridDim.y;
    int c = threadIdx.x;
    if (c >= C) return;
    int s0 = gstart[g], s1 = gstart[g+1];
    int len = s1 - s0;
    int per = (len + P - 1) / P;
    int rbeg = s0 + part*per, rend = rbeg + per; if (rend > s1) rend = s1;
    float sum = 0.f;
    for (int r = rbeg; r < rend; ++r) sum += srcm[(size_t)r*C + c];
    if (rend > rbeg) atomicAdd(&msum[g*C + c], sum);
}

__global__ void k_mlp1(const float* __restrict__ msum, const int* __restrict__ gstart,
                       const float* __restrict__ mW1, const float* __restrict__ mb1,
                       float* __restrict__ r1){
    int g = blockIdx.x, c = threadIdx.x;   // 128 threads
    int cnt = gstart[g+1] - gstart[g];
    float inv = 1.f / (float)(cnt > 1 ? cnt : 1);
    float acc = mb1[c];
    for (int k=0;k<128;k++) acc = fmaf(msum[g*128+k]*inv, mW1[k*128+c], acc);
    r1[g*128+c] = fmaxf(acc, 0.f);
}

__global__ void k_mlp2(const float* __restrict__ msum2, const int* __restrict__ gstart,
                       const float* __restrict__ mW2, const float* __restrict__ mb2,
                       float* __restrict__ r2){
    int g = blockIdx.x, c = threadIdx.x;
    if (c >= 32) return;
    int cnt = gstart[g+1] - gstart[g];
    float inv = 1.f / (float)(cnt > 1 ? cnt : 1);
    float acc = mb2[c];
    for (int k=0;k<32;k++) acc = fmaf(msum2[g*32+k]*inv, mW2[k*32+c], acc);
    r2[g*32+c] = fmaxf(acc, 0.f);
}

// ---------------- GEMM2: y2 = ((h + r1[batch]) @ W2) * dinv[row] ----------------
__global__ __launch_bounds__(256) void k_gemm2(const float* __restrict__ h, const float* __restrict__ vn,
                                               const int* __restrict__ batch, const float* __restrict__ W2,
                                               const float* __restrict__ dinv, float* __restrict__ y2, int N){
    __shared__ float W2s[128*32];   // 16 KB
    int t = threadIdx.x;
    {
        float4* Wl = (float4*)W2s;
        const float4* Wg = (const float4*)W2;
        #pragma unroll
        for (int i=0;i<4;i++) Wl[t + i*256] = Wg[t + i*256];
    }
    __syncthreads();
    int row0 = blockIdx.x*64;
    int tc = t & 7, trg = t >> 3;          // cols 4tc..4tc+3, rows 2trg, 2trg+1
    int ra = row0 + 2*trg, rb = ra + 1;
    bool oka = ra < N, okb = rb < N;
    const float* hpa = h + (size_t)(oka ? ra : 0)*128;
    const float* hpb = h + (size_t)(okb ? rb : 0)*128;
    const float* vpa = vn + (size_t)(oka ? batch[ra] : 0)*128;
    const float* vpb = vn + (size_t)(okb ? batch[rb] : 0)*128;
    float4 acca={0,0,0,0}, accb={0,0,0,0};
    for (int k=0;k<128;k+=4){
        float4 w0 = ld4(&W2s[(k+0)*32 + tc*4]);
        float4 w1 = ld4(&W2s[(k+1)*32 + tc*4]);
        float4 w2 = ld4(&W2s[(k+2)*32 + tc*4]);
        float4 w3 = ld4(&W2s[(k+3)*32 + tc*4]);
        {
            float4 a = ld4(hpa + k), b = ld4(vpa + k);
            a.x+=b.x; a.y+=b.y; a.z+=b.z; a.w+=b.w;
            acca.x += a.x*w0.x + a.y*w1.x + a.z*w2.x + a.w*w3.x;
            acca.y += a.x*w0.y + a.y*w1.y + a.z*w2.y + a.w*w3.y;
            acca.z += a.x*w0.z + a.y*w1.z + a.z*w2.z + a.w*w3.z;
            acca.w += a.x*w0.w + a.y*w1.w + a.z*w2.w + a.w*w3.w;
        }
        {
            float4 a = ld4(hpb + k), b = ld4(vpb + k);
            a.x+=b.x; a.y+=b.y; a.z+=b.z; a.w+=b.w;
            accb.x += a.x*w0.x + a.y*w1.x + a.z*w2.x + a.w*w3.x;
            accb.y += a.x*w0.y + a.y*w1.y + a.z*w2.y + a.w*w3.y;
            accb.z += a.x*w0.z + a.y*w1.z + a.z*w2.z + a.w*w3.z;
            accb.w += a.x*w0.w + a.y*w1.w + a.z*w2.w + a.w*w3.w;
        }
    }
    if (oka){ float dv = dinv[ra]; float4 o; o.x=acca.x*dv;o.y=acca.y*dv;o.z=acca.z*dv;o.w=acca.w*dv;
              st4(&y2[(size_t)ra*32 + tc*4], o); }
    if (okb){ float dv = dinv[rb]; float4 o; o.x=accb.x*dv;o.y=accb.y*dv;o.z=accb.z*dv;o.w=accb.w*dv;
              st4(&y2[(size_t)rb*32 + tc*4], o); }
}

// ---------------- aggregate layer 2 + bias -> Z (d_out) ----------------
__global__ void k_agg2(const float* __restrict__ y2, const float* __restrict__ dinv,
                       const float* __restrict__ b2, const int* __restrict__ rs,
                       const int* __restrict__ csr, float* __restrict__ Z, int N){
    int wid = (int)((blockIdx.x*blockDim.x + threadIdx.x) >> 6);
    if (wid >= N) return;
    int lane = threadIdx.x & 63, half = lane>>5, hl = lane&31;
    int beg = rs[wid], end = rs[wid+1], len = end-beg;
    int len0 = (len+1)>>1;
    int hbeg = beg + (half? len0:0);
    int hlen = half? (len-len0) : len0;
    float acc = (half==0) ? y2[(size_t)wid*32 + hl] : 0.f;
    int iters = (len0+31)>>5;
    for (int c=0;c<iters;c++){
        int o = c*32+hl;
        int idx = (o<hlen)? csr[hbeg+o] : 0;
        int nb = hlen - c*32;
        int tmax = len0 - c*32; if (tmax > 32) tmax = 32;
        for (int tt=0;tt<tmax;++tt){
            int s = __shfl(idx, (half<<5)+tt);
            float v = y2[(size_t)s*32 + hl];
            if (tt<nb) acc += v;
        }
    }
    acc += __shfl_xor(acc, 32);
    if (half==0) Z[(size_t)wid*32+hl] = dinv[wid]*acc + b2[hl];
}

// ---------------- add virtual node contribution + softmax (in-place on d_out) ----------------
__global__ void k_softmax(float* __restrict__ Z, const float* __restrict__ r2,
                          const int* __restrict__ batch, int N){
    int r = blockIdx.x*8 + (threadIdx.x>>5);
    int c = threadIdx.x & 31;
    if (r >= N) return;
    float z = Z[(size_t)r*32+c] + r2[batch[r]*32 + c];
    float m = z;
    #pragma unroll
    for (int off=16; off>=1; off>>=1) m = fmaxf(m, __shfl_xor(m, off));
    float e = expf(z - m);
    float s = e;
    #pragma unroll
    for (int off=16; off>=1; off>>=1) s += __shfl_xor(s, off);
    Z[(size_t)r*32+c] = e / s;
}

extern "C" void kernel_launch(void* const* d_in, const int* in_sizes, int n_in,
                              void* d_out, int out_size, void* d_ws, size_t ws_size,
                              hipStream_t stream){
    const float* X   = (const float*)d_in[0];
    const float* W1  = (const float*)d_in[1];
    const float* b1  = (const float*)d_in[2];
    const float* W2  = (const float*)d_in[3];
    const float* b2  = (const float*)d_in[4];
    const float* mW1 = (const float*)d_in[5];
    const float* mb1 = (const float*)d_in[6];
    const float* mW2 = (const float*)d_in[7];
    const float* mb2 = (const float*)d_in[8];
    const int*   ei  = (const int*)d_in[9];    // int32 on device (jax x64 disabled)
    const int*   batch = (const int*)d_in[10];
    int N = in_sizes[0] / 128;
    int E = in_sizes[9] / 2;
    const int* src = ei;
    const int* dst = ei + E;
    float* Zout = (float*)d_out;

    char* wsp = (char*)d_ws;
    size_t off = 0;
    auto alloc = [&](size_t bytes)->char*{
        char* p = wsp + off; off += (bytes + 255) & ~(size_t)255; return p;
    };
    // zero zone (one memset per call)
    int*   deg   = (int*)  alloc((size_t)N*4);
    int*   cur   = (int*)  alloc((size_t)N*4);
    float* msum  = (float*)alloc((size_t)GNUM*128*4);
    float* msum2 = (float*)alloc((size_t)GNUM*32*4);
    size_t zero_bytes = off;
    // rest
    int*   rs    = (int*)  alloc((size_t)(N+1)*4);
    int*   bsum  = (int*)  alloc(64*4);
    int*   gstart= (int*)  alloc((GNUM+1)*4);
    int*   csr   = (int*)  alloc((size_t)E*4);
    float* dinvp = (float*)alloc((size_t)N*4);
    float* y     = (float*)alloc((size_t)N*128*4);
    float* h     = (float*)alloc((size_t)N*128*4);
    float* y2    = (float*)alloc((size_t)N*32*4);
    float* r1buf = (float*)alloc((size_t)GNUM*128*4);
    float* r2buf = (float*)alloc((size_t)GNUM*32*4);
    (void)ws_size; (void)n_in; (void)out_size;

    hipMemsetAsync(d_ws, 0, zero_bytes, stream);

    const int TB = 256;
    int B1 = (N + 1023)/1024;   // 49 for N=50000 (must stay <= 64)

    k_degree<<<(E+TB-1)/TB, TB, 0, stream>>>(dst, E, deg);
    k_dinv  <<<(N+TB-1)/TB, TB, 0, stream>>>(deg, dinvp, N);
    k_scan_blocks<<<B1, 256, 0, stream>>>(deg, rs, bsum, N);
    k_scan_mid   <<<1, 64, 0, stream>>>(bsum, B1);
    k_scan_add   <<<B1, 256, 0, stream>>>(rs, bsum, N, E);
    k_fill  <<<(E+TB-1)/TB, TB, 0, stream>>>(src, dst, E, rs, cur, csr);

    k_gemm1 <<<(N+31)/32, 256, 0, stream>>>(X, W1, dinvp, y, N);
    k_agg1  <<<(N+3)/4, 256, 0, stream>>>(y, dinvp, b1, rs, csr, h, N);

    k_bounds<<<1, 128, 0, stream>>>(batch, N, gstart);
    k_mpool <<<dim3(GNUM,8), 128, 0, stream>>>(h, gstart, msum, 128);
    k_mlp1  <<<GNUM, 128, 0, stream>>>(msum, gstart, mW1, mb1, r1buf);

    k_gemm2 <<<(N+63)/64, 256, 0, stream>>>(h, r1buf, batch, W2, dinvp, y2, N);
    k_agg2  <<<(N+3)/4, 256, 0, stream>>>(y2, dinvp, b2, rs, csr, Zout, N);

    k_mpool <<<dim3(GNUM,8), 64, 0, stream>>>(Zout, gstart, msum2, 32);
    k_mlp2  <<<GNUM, 64, 0, stream>>>(msum2, gstart, mW2, mb2, r2buf);
    k_softmax<<<(N+7)/8, 256, 0, stream>>>(Zout, r2buf, batch, N);
}

// Round 2
// 325.380 us; speedup vs baseline: 1.4949x; 1.4949x over previous
//
#include <hip/hip_runtime.h>
#include <hip/hip_bf16.h>
#include <hip/hip_fp16.h>

#define DEV_INLINE __device__ __forceinline__

static DEV_INLINE float4 ld4(const float* p){ return *reinterpret_cast<const float4*>(p); }
static DEV_INLINE void st4(float* p, float4 v){ *reinterpret_cast<float4*>(p) = v; }

#define GNUM 64
#define CHUNK 4096
#define MAXNB 1024   // supports N up to 131072 (bucket = dst>>7)

// ======================= bucketed CSR build =======================
// Edges are partitioned by dst>>7 (128 nodes per bucket). (src,dst) packed in
// one u32 (N < 65536). Per-bucket processing turns random TCC atomics and
// scattered line-dirtying writes into LDS atomics + localized writes.

__global__ __launch_bounds__(256) void k_bucket_hist(const int* __restrict__ dst, int E, int NB,
                                                     int* __restrict__ bcnt){
    __shared__ int cnt[MAXNB];
    int t = threadIdx.x; int base0 = blockIdx.x*CHUNK;
    for (int i=t;i<NB;i+=256) cnt[i]=0;
    __syncthreads();
    int tot = E - base0; if (tot > CHUNK) tot = CHUNK;
    #pragma unroll
    for (int k=0;k<16;k++){
        int o = t + k*256;
        if (o < tot) atomicAdd(&cnt[dst[base0+o]>>7], 1);
    }
    __syncthreads();
    for (int i=t;i<NB;i+=256) if (cnt[i]) atomicAdd(&bcnt[i], cnt[i]);
}

// exclusive scan of bcnt[0..NB) -> bbase; bbase[NB]=E.  one block, NB<=1024.
__global__ void k_scan_nb(const int* __restrict__ bcnt, int* __restrict__ bbase, int NB, int E){
    __shared__ int ws[4];
    int t = threadIdx.x;
    int i0 = t*4;
    int c0=(i0+0<NB)?bcnt[i0+0]:0, c1=(i0+1<NB)?bcnt[i0+1]:0;
    int c2=(i0+2<NB)?bcnt[i0+2]:0, c3=(i0+3<NB)?bcnt[i0+3]:0;
    int tsum=c0+c1+c2+c3;
    int lane=t&63, w=t>>6;
    int x=tsum;
    for (int off=1;off<64;off<<=1){ int yv=__shfl_up(x,off); if (lane>=off) x+=yv; }
    if (lane==63) ws[w]=x;
    __syncthreads();
    if (t==0){ int a=0; for (int i=0;i<4;i++){ int tmp=ws[i]; ws[i]=a; a+=tmp; } }
    __syncthreads();
    int ex = x - tsum + ws[w];
    if (i0+0<NB) bbase[i0+0]=ex; ex+=c0;
    if (i0+1<NB) bbase[i0+1]=ex; ex+=c1;
    if (i0+2<NB) bbase[i0+2]=ex; ex+=c2;
    if (i0+3<NB) bbase[i0+3]=ex;
    if (t==0) bbase[NB]=E;
}

__global__ __launch_bounds__(256) void k_bucket_scatter(const int* __restrict__ src, const int* __restrict__ dst,
                                                        int E, int NB, const int* __restrict__ bbase,
                                                        int* __restrict__ bfill, unsigned* __restrict__ ebuf){
    __shared__ int cnt[MAXNB];
    __shared__ int pfx[MAXNB];
    __shared__ int gbase[MAXNB];
    __shared__ unsigned stage[CHUNK];
    __shared__ int ws[4];
    int t = threadIdx.x; int base0 = blockIdx.x*CHUNK;
    int tot = E - base0; if (tot > CHUNK) tot = CHUNK;
    for (int i=t;i<NB;i+=256) cnt[i]=0;
    __syncthreads();
    unsigned v[16]; int rk[16];
    #pragma unroll
    for (int k=0;k<16;k++){
        int o = t + k*256;
        if (o < tot){
            int e = base0 + o;
            int s = src[e], d = dst[e];
            v[k] = (unsigned)s | ((unsigned)d<<16);
            rk[k] = atomicAdd(&cnt[d>>7], 1);
        } else { v[k]=0u; rk[k]=-1; }
    }
    __syncthreads();
    // exclusive scan cnt -> pfx
    int i0 = t*4;
    int c0=(i0+0<NB)?cnt[i0+0]:0, c1=(i0+1<NB)?cnt[i0+1]:0;
    int c2=(i0+2<NB)?cnt[i0+2]:0, c3=(i0+3<NB)?cnt[i0+3]:0;
    int tsum=c0+c1+c2+c3;
    int lane=t&63, w=t>>6;
    int x=tsum;
    for (int off=1;off<64;off<<=1){ int yv=__shfl_up(x,off); if (lane>=off) x+=yv; }
    if (lane==63) ws[w]=x;
    __syncthreads();
    if (t==0){ int a=0; for (int i=0;i<4;i++){ int tmp=ws[i]; ws[i]=a; a+=tmp; } }
    __syncthreads();
    int ex = x - tsum + ws[w];
    if (i0+0<NB) pfx[i0+0]=ex; ex+=c0;
    if (i0+1<NB) pfx[i0+1]=ex; ex+=c1;
    if (i0+2<NB) pfx[i0+2]=ex; ex+=c2;
    if (i0+3<NB) pfx[i0+3]=ex;
    __syncthreads();
    // reserve global slices per bucket (few atomics, small array)
    for (int i=t;i<NB;i+=256){
        int c = cnt[i];
        gbase[i] = c ? (bbase[i] + atomicAdd(&bfill[i], c)) : 0;
    }
    __syncthreads();
    // bucket-major stage in LDS
    #pragma unroll
    for (int k=0;k<16;k++) if (rk[k]>=0){ int b = (int)(v[k]>>23); stage[pfx[b]+rk[k]] = v[k]; }
    __syncthreads();
    // coalesced-ish writeout (consecutive j mostly share a bucket)
    for (int j=t;j<tot;j+=256){
        unsigned u = stage[j];
        int b = (int)(u>>23);
        ebuf[gbase[b] + (j - pfx[b])] = u;
    }
}

__global__ void k_bucket_deg(const unsigned* __restrict__ ebuf, const int* __restrict__ bbase,
                             int* __restrict__ deg, int N){
    __shared__ int c2[128];
    int b = blockIdx.x, t = threadIdx.x;
    if (t<128) c2[t]=0;
    __syncthreads();
    int s0=bbase[b], s1=bbase[b+1];
    for (int j=s0+t; j<s1; j+=256){
        unsigned u = ebuf[j];
        atomicAdd(&c2[(u>>16)&127], 1);
    }
    __syncthreads();
    int node = (b<<7)+t;
    if (t<128 && node<N) deg[node]=c2[t];
}

__global__ void k_bucket_fill(const unsigned* __restrict__ ebuf, const int* __restrict__ bbase,
                              const int* __restrict__ rs, int* __restrict__ csr, int N){
    __shared__ int rsl[128]; __shared__ int cur[128];
    int b = blockIdx.x, t = threadIdx.x;
    int node = (b<<7)+t;
    if (t<128){ cur[t]=0; rsl[t] = (node<N)? rs[node] : 0; }
    __syncthreads();
    int s0=bbase[b], s1=bbase[b+1];
    for (int j=s0+t; j<s1; j+=256){
        unsigned u = ebuf[j];
        int ld = (u>>16)&127;
        int p = atomicAdd(&cur[ld], 1);
        csr[rsl[ld]+p] = (int)(u & 0xffffu);
    }
}

// ---------------- dinv ----------------
__global__ void k_dinv(const int* __restrict__ deg, float* __restrict__ dinv, int N){
    int i = blockIdx.x*256 + threadIdx.x;
    if (i < N) dinv[i] = rsqrtf((float)(deg[i] + 1));
}

// ---------------- exclusive scan of deg -> row_start ----------------
__global__ void k_scan_blocks(const int* __restrict__ deg, int* __restrict__ rs,
                              int* __restrict__ bsum, int N){
    __shared__ int ws[4];
    int t = threadIdx.x;
    int base = blockIdx.x*1024 + t*4;
    int v0 = (base+0<N)? deg[base+0]:0;
    int v1 = (base+1<N)? deg[base+1]:0;
    int v2 = (base+2<N)? deg[base+2]:0;
    int v3 = (base+3<N)? deg[base+3]:0;
    int tsum = v0+v1+v2+v3;
    int lane = t & 63, w = t >> 6;
    int x = tsum;
    for (int off=1; off<64; off<<=1){
        int yv = __shfl_up(x, off);
        if (lane >= off) x += yv;
    }
    if (lane == 63) ws[w] = x;
    __syncthreads();
    if (t == 0){
        int a = 0;
        for (int i=0;i<4;i++){ int tmp=ws[i]; ws[i]=a; a+=tmp; }
    }
    __syncthreads();
    int ex = x - tsum + ws[w];
    if (base+0<N) rs[base+0] = ex; ex += v0;
    if (base+1<N) rs[base+1] = ex; ex += v1;
    if (base+2<N) rs[base+2] = ex; ex += v2;
    if (base+3<N) rs[base+3] = ex;
    if (t == 255) bsum[blockIdx.x] = ws[3] + x;
}

__global__ void k_scan_mid(int* __restrict__ bsum, int B){  // B <= 64
    int lane = threadIdx.x;
    int v = (lane < B)? bsum[lane] : 0;
    int x = v;
    for (int off=1; off<64; off<<=1){
        int yv = __shfl_up(x, off);
        if (lane >= off) x += yv;
    }
    if (lane < B) bsum[lane] = x - v;
}

__global__ void k_scan_add(int* __restrict__ rs, const int* __restrict__ bsum, int N, int E){
    int base = blockIdx.x*1024 + threadIdx.x*4;
    int off = bsum[blockIdx.x];
    #pragma unroll
    for (int j=0;j<4;j++) if (base+j < N) rs[base+j] += off;
    if (blockIdx.x==0 && threadIdx.x==0) rs[N] = E;
}

// ---------------- GEMM1: y = (X @ W1) * dinv[row], stored fp16 ----------------
__global__ __launch_bounds__(256) void k_gemm1(const float* __restrict__ X, const float* __restrict__ W1,
                                               const float* __restrict__ dinv, __half* __restrict__ yh, int N){
    __shared__ float Ws[128*128];   // 64 KB
    __shared__ float Xs[32*128];    // 16 KB
    int t = threadIdx.x;
    int row0 = blockIdx.x * 32;
    {
        const float4* Wg = (const float4*)W1;
        float4* Wl = (float4*)Ws;
        #pragma unroll
        for (int i=0;i<16;i++) Wl[t + i*256] = Wg[t + i*256];
    }
    {
        float4* Xl = (float4*)Xs;
        const float4* Xg = (const float4*)X;
        #pragma unroll
        for (int i=0;i<4;i++){
            int fi = t + i*256;
            int r = fi >> 5;
            float4 v = make_float4(0.f,0.f,0.f,0.f);
            if (row0 + r < N) v = Xg[(size_t)(row0+r)*32 + (fi & 31)];
            Xl[fi] = v;
        }
    }
    __syncthreads();
    int tc = t & 31, tr = t >> 5;
    float4 acc0={0,0,0,0}, acc1={0,0,0,0}, acc2={0,0,0,0}, acc3={0,0,0,0};
    for (int k=0;k<128;k+=4){
        float4 w0 = ld4(&Ws[(k+0)*128 + tc*4]);
        float4 w1 = ld4(&Ws[(k+1)*128 + tc*4]);
        float4 w2 = ld4(&Ws[(k+2)*128 + tc*4]);
        float4 w3 = ld4(&Ws[(k+3)*128 + tc*4]);
        #define ROWSTEP(ACC, RR) { float4 xr = ld4(&Xs[(4*tr+(RR))*128 + k]); \
            ACC.x += xr.x*w0.x + xr.y*w1.x + xr.z*w2.x + xr.w*w3.x; \
            ACC.y += xr.x*w0.y + xr.y*w1.y + xr.z*w2.y + xr.w*w3.y; \
            ACC.z += xr.x*w0.z + xr.y*w1.z + xr.z*w2.z + xr.w*w3.z; \
            ACC.w += xr.x*w0.w + xr.y*w1.w + xr.z*w2.w + xr.w*w3.w; }
        ROWSTEP(acc0,0) ROWSTEP(acc1,1) ROWSTEP(acc2,2) ROWSTEP(acc3,3)
        #undef ROWSTEP
    }
    #define STORESTEP(ACC, RR) { int row = row0 + 4*tr + (RR); if (row < N){ \
        float dv = dinv[row]; \
        __half2 p0 = __floats2half2_rn(ACC.x*dv, ACC.y*dv); \
        __half2 p1 = __floats2half2_rn(ACC.z*dv, ACC.w*dv); \
        uint2 stv; stv.x = *(unsigned*)&p0; stv.y = *(unsigned*)&p1; \
        *reinterpret_cast<uint2*>(&yh[(size_t)row*128 + tc*4]) = stv; } }
    STORESTEP(acc0,0) STORESTEP(acc1,1) STORESTEP(acc2,2) STORESTEP(acc3,3)
    #undef STORESTEP
}

// ---------------- aggregate layer 1 (fp16 gathers) + bias + ELU -> h ----------------
__global__ void k_agg1(const __half* __restrict__ yh, const float* __restrict__ dinv,
                       const float* __restrict__ b1, const int* __restrict__ rs,
                       const int* __restrict__ csr, float* __restrict__ h, int N){
    int wid = (int)((blockIdx.x * blockDim.x + threadIdx.x) >> 6);
    if (wid >= N) return;
    int lane = threadIdx.x & 63;
    int half = lane >> 5, hl = lane & 31;
    int beg = rs[wid], end = rs[wid+1];
    int len = end - beg;
    int len0 = (len + 1) >> 1;
    int hbeg = beg + (half ? len0 : 0);
    int hlen = half ? (len - len0) : len0;
    float4 acc = make_float4(0.f,0.f,0.f,0.f);
    if (half == 0){
        uint2 u = *reinterpret_cast<const uint2*>(&yh[(size_t)wid*128 + hl*4]);
        __half2 h0 = *reinterpret_cast<__half2*>(&u.x);
        __half2 h1 = *reinterpret_cast<__half2*>(&u.y);
        float2 f0 = __half22float2(h0), f1 = __half22float2(h1);
        acc.x=f0.x; acc.y=f0.y; acc.z=f1.x; acc.w=f1.y;
    }
    int iters = (len0 + 31) >> 5;
    for (int c=0;c<iters;c++){
        int o = c*32 + hl;
        int idx = (o < hlen) ? csr[hbeg + o] : 0;
        int nb = hlen - c*32;
        int tmax = len0 - c*32; if (tmax > 32) tmax = 32;
        for (int tt=0; tt<tmax; ++tt){
            int s = __shfl(idx, (half<<5) + tt);
            uint2 u = *reinterpret_cast<const uint2*>(&yh[(size_t)s*128 + hl*4]);
            __half2 h0 = *reinterpret_cast<__half2*>(&u.x);
            __half2 h1 = *reinterpret_cast<__half2*>(&u.y);
            float2 f0 = __half22float2(h0), f1 = __half22float2(h1);
            if (tt < nb){ acc.x+=f0.x; acc.y+=f0.y; acc.z+=f1.x; acc.w+=f1.y; }
        }
    }
    acc.x += __shfl_xor(acc.x, 32);
    acc.y += __shfl_xor(acc.y, 32);
    acc.z += __shfl_xor(acc.z, 32);
    acc.w += __shfl_xor(acc.w, 32);
    if (half == 0){
        float dv = dinv[wid];
        float4 bb = ld4(&b1[hl*4]);
        float4 o;
        o.x = dv*acc.x + bb.x; o.y = dv*acc.y + bb.y;
        o.z = dv*acc.z + bb.z; o.w = dv*acc.w + bb.w;
        o.x = o.x > 0.f ? o.x : expm1f(o.x);
        o.y = o.y > 0.f ? o.y : expm1f(o.y);
        o.z = o.z > 0.f ? o.z : expm1f(o.z);
        o.w = o.w > 0.f ? o.w : expm1f(o.w);
        st4(&h[(size_t)wid*128 + hl*4], o);
    }
}

// ---------------- graph boundaries ----------------
__global__ void k_bounds(const int* __restrict__ batch, int N, int* __restrict__ gstart){
    int g = threadIdx.x;
    if (g > GNUM) return;
    int lo = 0, hi = N;
    while (lo < hi){ int mid = (lo+hi)>>1; if (batch[mid] < g) lo = mid+1; else hi = mid; }
    gstart[g] = lo;
}

// ---------------- mean-pool partial sums ----------------
__global__ void k_mpool(const float* __restrict__ srcm, const int* __restrict__ gstart,
                        float* __restrict__ msum, int C){
    int g = blockIdx.x, part = blockIdx.y, P = gridDim.y;
    int c = threadIdx.x;
    if (c >= C) return;
    int s0 = gstart[g], s1 = gstart[g+1];
    int len = s1 - s0;
    int per = (len + P - 1) / P;
    int rbeg = s0 + part*per, rend = rbeg + per; if (rend > s1) rend = s1;
    float sum = 0.f;
    for (int r = rbeg; r < rend; ++r) sum += srcm[(size_t)r*C + c];
    if (rend > rbeg) atomicAdd(&msum[g*C + c], sum);
}

__global__ void k_mlp1(const float* __restrict__ msum, const int* __restrict__ gstart,
                       const float* __restrict__ mW1, const float* __restrict__ mb1,
                       float* __restrict__ r1){
    int g = blockIdx.x, c = threadIdx.x;
    int cnt = gstart[g+1] - gstart[g];
    float inv = 1.f / (float)(cnt > 1 ? cnt : 1);
    float acc = mb1[c];
    for (int k=0;k<128;k++) acc = fmaf(msum[g*128+k]*inv, mW1[k*128+c], acc);
    r1[g*128+c] = fmaxf(acc, 0.f);
}

__global__ void k_mlp2(const float* __restrict__ msum2, const int* __restrict__ gstart,
                       const float* __restrict__ mW2, const float* __restrict__ mb2,
                       float* __restrict__ r2){
    int g = blockIdx.x, c = threadIdx.x;
    if (c >= 32) return;
    int cnt = gstart[g+1] - gstart[g];
    float inv = 1.f / (float)(cnt > 1 ? cnt : 1);
    float acc = mb2[c];
    for (int k=0;k<32;k++) acc = fmaf(msum2[g*32+k]*inv, mW2[k*32+c], acc);
    r2[g*32+c] = fmaxf(acc, 0.f);
}

// ---------------- GEMM2: y2 = ((h + r1[batch]) @ W2) * dinv[row] ----------------
__global__ __launch_bounds__(256) void k_gemm2(const float* __restrict__ h, const float* __restrict__ vn,
                                               const int* __restrict__ batch, const float* __restrict__ W2,
                                               const float* __restrict__ dinv, float* __restrict__ y2, int N){
    __shared__ float W2s[128*32];
    int t = threadIdx.x;
    {
        float4* Wl = (float4*)W2s;
        const float4* Wg = (const float4*)W2;
        #pragma unroll
        for (int i=0;i<4;i++) Wl[t + i*256] = Wg[t + i*256];
    }
    __syncthreads();
    int row0 = blockIdx.x*64;
    int tc = t & 7, trg = t >> 3;
    int ra = row0 + 2*trg, rb = ra + 1;
    bool oka = ra < N, okb = rb < N;
    const float* hpa = h + (size_t)(oka ? ra : 0)*128;
    const float* hpb = h + (size_t)(okb ? rb : 0)*128;
    const float* vpa = vn + (size_t)(oka ? batch[ra] : 0)*128;
    const float* vpb = vn + (size_t)(okb ? batch[rb] : 0)*128;
    float4 acca={0,0,0,0}, accb={0,0,0,0};
    for (int k=0;k<128;k+=4){
        float4 w0 = ld4(&W2s[(k+0)*32 + tc*4]);
        float4 w1 = ld4(&W2s[(k+1)*32 + tc*4]);
        float4 w2 = ld4(&W2s[(k+2)*32 + tc*4]);
        float4 w3 = ld4(&W2s[(k+3)*32 + tc*4]);
        {
            float4 a = ld4(hpa + k), b = ld4(vpa + k);
            a.x+=b.x; a.y+=b.y; a.z+=b.z; a.w+=b.w;
            acca.x += a.x*w0.x + a.y*w1.x + a.z*w2.x + a.w*w3.x;
            acca.y += a.x*w0.y + a.y*w1.y + a.z*w2.y + a.w*w3.y;
            acca.z += a.x*w0.z + a.y*w1.z + a.z*w2.z + a.w*w3.z;
            acca.w += a.x*w0.w + a.y*w1.w + a.z*w2.w + a.w*w3.w;
        }
        {
            float4 a = ld4(hpb + k), b = ld4(vpb + k);
            a.x+=b.x; a.y+=b.y; a.z+=b.z; a.w+=b.w;
            accb.x += a.x*w0.x + a.y*w1.x + a.z*w2.x + a.w*w3.x;
            accb.y += a.x*w0.y + a.y*w1.y + a.z*w2.y + a.w*w3.y;
            accb.z += a.x*w0.z + a.y*w1.z + a.z*w2.z + a.w*w3.z;
            accb.w += a.x*w0.w + a.y*w1.w + a.z*w2.w + a.w*w3.w;
        }
    }
    if (oka){ float dv = dinv[ra]; float4 o; o.x=acca.x*dv;o.y=acca.y*dv;o.z=acca.z*dv;o.w=acca.w*dv;
              st4(&y2[(size_t)ra*32 + tc*4], o); }
    if (okb){ float dv = dinv[rb]; float4 o; o.x=accb.x*dv;o.y=accb.y*dv;o.z=accb.z*dv;o.w=accb.w*dv;
              st4(&y2[(size_t)rb*32 + tc*4], o); }
}

// ---------------- aggregate layer 2 + bias -> Z ----------------
__global__ void k_agg2(const float* __restrict__ y2, const float* __restrict__ dinv,
                       const float* __restrict__ b2, const int* __restrict__ rs,
                       const int* __restrict__ csr, float* __restrict__ Z, int N){
    int wid = (int)((blockIdx.x*blockDim.x + threadIdx.x) >> 6);
    if (wid >= N) return;
    int lane = threadIdx.x & 63, half = lane>>5, hl = lane&31;
    int beg = rs[wid], end = rs[wid+1], len = end-beg;
    int len0 = (len+1)>>1;
    int hbeg = beg + (half? len0:0);
    int hlen = half? (len-len0) : len0;
    float acc = (half==0) ? y2[(size_t)wid*32 + hl] : 0.f;
    int iters = (len0+31)>>5;
    for (int c=0;c<iters;c++){
        int o = c*32+hl;
        int idx = (o<hlen)? csr[hbeg+o] : 0;
        int nb = hlen - c*32;
        int tmax = len0 - c*32; if (tmax > 32) tmax = 32;
        for (int tt=0;tt<tmax;++tt){
            int s = __shfl(idx, (half<<5)+tt);
            float v = y2[(size_t)s*32 + hl];
            if (tt<nb) acc += v;
        }
    }
    acc += __shfl_xor(acc, 32);
    if (half==0) Z[(size_t)wid*32+hl] = dinv[wid]*acc + b2[hl];
}

// ---------------- + virtual node + softmax ----------------
__global__ void k_softmax(float* __restrict__ Z, const float* __restrict__ r2,
                          const int* __restrict__ batch, int N){
    int r = blockIdx.x*8 + (threadIdx.x>>5);
    int c = threadIdx.x & 31;
    if (r >= N) return;
    float z = Z[(size_t)r*32+c] + r2[batch[r]*32 + c];
    float m = z;
    #pragma unroll
    for (int off=16; off>=1; off>>=1) m = fmaxf(m, __shfl_xor(m, off));
    float e = expf(z - m);
    float s = e;
    #pragma unroll
    for (int off=16; off>=1; off>>=1) s += __shfl_xor(s, off);
    Z[(size_t)r*32+c] = e / s;
}

extern "C" void kernel_launch(void* const* d_in, const int* in_sizes, int n_in,
                              void* d_out, int out_size, void* d_ws, size_t ws_size,
                              hipStream_t stream){
    const float* X   = (const float*)d_in[0];
    const float* W1  = (const float*)d_in[1];
    const float* b1  = (const float*)d_in[2];
    const float* W2  = (const float*)d_in[3];
    const float* b2  = (const float*)d_in[4];
    const float* mW1 = (const float*)d_in[5];
    const float* mb1 = (const float*)d_in[6];
    const float* mW2 = (const float*)d_in[7];
    const float* mb2 = (const float*)d_in[8];
    const int*   ei  = (const int*)d_in[9];
    const int*   batch = (const int*)d_in[10];
    int N = in_sizes[0] / 128;
    int E = in_sizes[9] / 2;
    const int* src = ei;
    const int* dst = ei + E;
    float* Zout = (float*)d_out;

    char* wsp = (char*)d_ws;
    size_t off = 0;
    auto alloc = [&](size_t bytes)->char*{
        char* p = wsp + off; off += (bytes + 255) & ~(size_t)255; return p;
    };
    // zero zone
    int*   bcnt  = (int*)  alloc((size_t)MAXNB*4);
    int*   bfill = (int*)  alloc((size_t)MAXNB*4);
    float* msum  = (float*)alloc((size_t)GNUM*128*4);
    float* msum2 = (float*)alloc((size_t)GNUM*32*4);
    size_t zero_bytes = off;
    // rest
    int*   bbase = (int*)  alloc((size_t)(MAXNB+1)*4);
    int*   deg   = (int*)  alloc((size_t)N*4);
    int*   rs    = (int*)  alloc((size_t)(N+1)*4);
    int*   bsum  = (int*)  alloc(64*4);
    int*   gstart= (int*)  alloc((GNUM+1)*4);
    unsigned* ebuf = (unsigned*)alloc((size_t)E*4);
    int*   csr   = (int*)  alloc((size_t)E*4);
    float* dinvp = (float*)alloc((size_t)N*4);
    __half* yh   = (__half*)alloc((size_t)N*128*2);
    float* h     = (float*)alloc((size_t)N*128*4);
    float* y2    = (float*)alloc((size_t)N*32*4);
    float* r1buf = (float*)alloc((size_t)GNUM*128*4);
    float* r2buf = (float*)alloc((size_t)GNUM*32*4);
    (void)ws_size; (void)n_in; (void)out_size;

    hipMemsetAsync(d_ws, 0, zero_bytes, stream);

    int NB = (N + 127) >> 7;            // 391 for N=50000 (<= MAXNB)
    int EB = (E + CHUNK-1) / CHUNK;     // 391 for E=1.6M
    int B1 = (N + 1023)/1024;           // 49 (<= 64)

    k_bucket_hist   <<<EB, 256, 0, stream>>>(dst, E, NB, bcnt);
    k_scan_nb       <<<1, 256, 0, stream>>>(bcnt, bbase, NB, E);
    k_bucket_scatter<<<EB, 256, 0, stream>>>(src, dst, E, NB, bbase, bfill, ebuf);
    k_bucket_deg    <<<NB, 256, 0, stream>>>(ebuf, bbase, deg, N);
    k_dinv          <<<(N+255)/256, 256, 0, stream>>>(deg, dinvp, N);
    k_scan_blocks   <<<B1, 256, 0, stream>>>(deg, rs, bsum, N);
    k_scan_mid      <<<1, 64, 0, stream>>>(bsum, B1);
    k_scan_add      <<<B1, 256, 0, stream>>>(rs, bsum, N, E);
    k_bucket_fill   <<<NB, 256, 0, stream>>>(ebuf, bbase, rs, csr, N);

    k_gemm1 <<<(N+31)/32, 256, 0, stream>>>(X, W1, dinvp, yh, N);
    k_agg1  <<<(N+3)/4, 256, 0, stream>>>(yh, dinvp, b1, rs, csr, h, N);

    k_bounds<<<1, 128, 0, stream>>>(batch, N, gstart);
    k_mpool <<<dim3(GNUM,8), 128, 0, stream>>>(h, gstart, msum, 128);
    k_mlp1  <<<GNUM, 128, 0, stream>>>(msum, gstart, mW1, mb1, r1buf);

    k_gemm2 <<<(N+63)/64, 256, 0, stream>>>(h, r1buf, batch, W2, dinvp, y2, N);
    k_agg2  <<<(N+3)/4, 256, 0, stream>>>(y2, dinvp, b2, rs, csr, Zout, N);

    k_mpool <<<dim3(GNUM,8), 64, 0, stream>>>(Zout, gstart, msum2, 32);
    k_mlp2  <<<GNUM, 64, 0, stream>>>(msum2, gstart, mW2, mb2, r2buf);
    k_softmax<<<(N+7)/8, 256, 0, stream>>>(Zout, r2buf, batch, N);
}